// Round 4
// baseline (353.697 us; speedup 1.0000x reference)
//
#include <hip/hip_runtime.h>

typedef short short8  __attribute__((ext_vector_type(8)));
typedef short short4v __attribute__((ext_vector_type(4)));
typedef float f32x4   __attribute__((ext_vector_type(4)));

#define MFMA_BF16(A,B,C) __builtin_amdgcn_mfma_f32_16x16x32_bf16((A),(B),(C),0,0,0)

__device__ __forceinline__ short bf16bits(float f){
  return (short)__builtin_bit_cast(unsigned short, static_cast<__bf16>(f));
}

// ---------------- fused preprocessing ----------------
// blocks [0,220): mask preprocessing  (region_masks -> allowed bits)
// blocks [220,988): K/V repack to bf16 in FRAGMENT-PERMUTED order:
//   Kb chunk layout  [h][t=key/16][f=d/32][c=key%16][Q=(d/8)%4][j=d%8]
//   VT chunk layout  [h][kc=key/32][m=d/16][c=d%16][Q=(key/8)%4][j=key%8]
// so that every attn ds_read_b128 sweeps 64 consecutive 16B chunks
// (1KB dense -> bank-conflict-free by construction, no XOR swizzle).
__global__ __launch_bounds__(256) void prep_kernel(const float* __restrict__ rm,
                                                   const float* __restrict__ k,
                                                   const float* __restrict__ v,
                                                   const float* __restrict__ rk,
                                                   const float* __restrict__ rv,
                                                   unsigned* __restrict__ allowed,
                                                   unsigned short* __restrict__ Kb,
                                                   unsigned short* __restrict__ VT){
  const int bid = blockIdx.x;
  if (bid < 220){
    int s = bid*256 + threadIdx.x;
    if (s >= 56320) return;
    int t = s / 3520;
    int rem = s - t*3520;
    int i = rem / 80;
    int j = rem - i*80;
    int y = 2*i, x = 2*j;
    bool bin[2];
    #pragma unroll
    for (int r=0;r<2;r++){
      const float* base = rm + (size_t)r*121*88*160;
      float acc;
      if (t == 0){
        const float* p0 = base + (size_t)(0*88 + y)*160 + x;
        acc = 0.25f*(p0[0]+p0[1]+p0[160]+p0[161]);
      } else {
        const float* pa = base + (size_t)((8*t-4)*88 + y)*160 + x;
        const float* pb = base + (size_t)((8*t-3)*88 + y)*160 + x;
        acc = 0.125f*(pa[0]+pa[1]+pa[160]+pa[161] + pb[0]+pb[1]+pb[160]+pb[161]);
      }
      bin[r] = acc > 0.5f;
    }
    unsigned bits = (bin[0]||bin[1]) ? 0u : 1u;
    if (bin[0]) bits |= 2u;
    if (bin[1]) bits |= 4u;
    allowed[s] = bits;
  } else {
    int idx = (bid-220)*256 + threadIdx.x;   // over 3*128*8*64 = 196608
    if (idx >= 3*128*8*64) return;
    int d   = idx & 63;
    int h   = (idx >> 6) & 7;
    int p   = (idx >> 9) & 127;
    int seg = idx >> 16;
    int low = idx & 65535;                   // (p*8+h)*64+d
    float kv_, vv_;
    if (seg == 0){ kv_ = k[low];                          vv_ = v[low]; }
    else         { kv_ = rk[(size_t)(seg-1)*65536 + low]; vv_ = rv[(size_t)(seg-1)*65536 + low]; }
    const int kk = seg*128 + p;              // key index within head, 0..383
    // K: tile t=kk>>4, row c=kk&15, frag f=d>>5, quad Qd=(d>>3)&3, elem j=d&7
    {
      const int t  = kk >> 4, ck = kk & 15;
      const int f  = d >> 5, Qd = (d >> 3) & 3, j = d & 7;
      Kb[(size_t)h*24576 + t*1024 + f*512 + (ck*4 + Qd)*8 + j] = (unsigned short)bf16bits(kv_);
    }
    // V^T: chunk kc=kk>>5, m=d>>4, row c=d&15, quad Qv=(kk>>3)&3, elem jv=kk&7
    {
      const int kc = kk >> 5, Qv = (kk >> 3) & 3, jv = kk & 7;
      const int m  = d >> 4, cv = d & 15;
      VT[(size_t)h*24576 + (kc*4 + m)*512 + (cv*4 + Qv)*8 + jv] = (unsigned short)bf16bits(vv_);
    }
  }
}

// ---------------- fused regional+base attention, LDS-staged ----------------
// 512 threads (8 waves) per (head, 256-query chunk). K (48KB) and V^T (48KB)
// are staged once per block as a PURE LINEAR memcpy (global layout is already
// fragment-permuted by prep) -> coalesced global reads, conflict-free
// ds_writes. Every hot-loop ds_read_b128 covers a dense 1KB run (64 lanes x
// consecutive 16B chunks) -> zero bank conflicts. Each wave owns 32 queries
// (two 16-col sets A/B sharing every K/V fragment read). 6 phases of
// {4 score tiles -> exp(s-8) unnormalized -> P chunks in LDS; 2 PV chunks}.
// P layout per wave/set: chunk ch=key16B-slot, addr = ch*256 + c*16 (dense on
// both write and read). LDS total = 48+48+32 = 128KB -> 1 block/CU,
// 2 waves/SIMD; __launch_bounds__(512,2) lifts the VGPR cap to 256 (round 3's
// default 128 spilled the accumulators: +137MB scratch WRITE_SIZE).
__global__ __launch_bounds__(512, 2) void attn_kernel(const float* __restrict__ q,
                                                      const unsigned* __restrict__ allowed,
                                                      const unsigned short* __restrict__ Kb,
                                                      const unsigned short* __restrict__ VT,
                                                      float* __restrict__ out){
  const int h    = blockIdx.y;
  const int wave = threadIdx.x >> 6;
  const int lane = threadIdx.x & 63;
  const int c    = lane & 15;        // query col within set / fragment row
  const int Q    = lane >> 4;        // quad

  __shared__ __align__(16) char Ks[49152];   // 24 tiles x 2 frags x 1KB
  __shared__ __align__(16) char Vs[49152];   // 48 (kc,m) chunks x 1KB
  __shared__ __align__(16) char Ps[32768];   // 8 waves x 2 sets x 2KB

  const int sA = blockIdx.x*256 + wave*32 + c;
  const int sB = sA + 16;

  // ---- early global loads (overlap with staging)
  const unsigned abA = allowed[sA], abB = allowed[sB];
  const float* qpA = q + ((size_t)sA*8 + h)*64 + Q*8;
  const float* qpB = q + ((size_t)sB*8 + h)*64 + Q*8;
  f32x4 qA0 = *(const f32x4*)(qpA);
  f32x4 qA1 = *(const f32x4*)(qpA+4);
  f32x4 qA2 = *(const f32x4*)(qpA+32);
  f32x4 qA3 = *(const f32x4*)(qpA+36);
  f32x4 qB0 = *(const f32x4*)(qpB);
  f32x4 qB1 = *(const f32x4*)(qpB+4);
  f32x4 qB2 = *(const f32x4*)(qpB+32);
  f32x4 qB3 = *(const f32x4*)(qpB+36);

  // ---- stage K and V^T: pure linear copy, 6KB of each per wave
  {
    const char* kg = (const char*)Kb + (size_t)h*49152;
    const char* vg = (const char*)VT + (size_t)h*49152;
    #pragma unroll
    for (int i=0;i<6;i++){
      const int off = wave*6144 + i*1024 + lane*16;
      short8 kval = *(const short8*)(kg + off);
      short8 vval = *(const short8*)(vg + off);
      *(short8*)(Ks + off) = kval;
      *(short8*)(Vs + off) = vval;
    }
  }

  // ---- bf16 Q fragments (B-operand): lane holds q[s(c)][d=Q*8+j (+32)]
  short8 fA0, fA1, fB0, fB1;
  #pragma unroll
  for (int j=0;j<4;j++){
    fA0[j] = bf16bits(qA0[j]); fA0[4+j] = bf16bits(qA1[j]);
    fA1[j] = bf16bits(qA2[j]); fA1[4+j] = bf16bits(qA3[j]);
    fB0[j] = bf16bits(qB0[j]); fB0[4+j] = bf16bits(qB1[j]);
    fB1[j] = bf16bits(qB2[j]); fB1[4+j] = bf16bits(qB3[j]);
  }

  __syncthreads();   // staged K/V visible to all waves

  // ---- dense per-lane fragment slots (no swizzle needed)
  const int fo = (c*4 + Q)*16;               // 16B slot within each 1KB chunk
  const char* kfb = Ks + fo;                 // + t*2048 + f*1024
  const char* vfb = Vs + fo;                 // + (kc*4+m)*1024
  char*       pwA = Ps + wave*4096 + (Q>>1)*256 + c*16 + (Q&1)*8;  // + i*512 (+2048 set B)
  const char* prA = Ps + wave*4096 + Q*256 + c*16;                 // + klp*1024 (+2048 set B)

  const float amA1 = (abA>>1)&1u ? 1.f : 0.f;
  const float amA2 = (abA>>2)&1u ? 1.f : 0.f;
  const float amB1 = (abB>>1)&1u ? 1.f : 0.f;
  const float amB2 = (abB>>2)&1u ? 1.f : 0.f;

  float lbA=0.f, lrA=0.f, lbB=0.f, lrB=0.f;
  f32x4 aA0[4], aA1[4], aB0[4], aB1[4];
  #pragma unroll
  for (int m=0;m<4;m++){
    aA0[m]=(f32x4){0,0,0,0}; aA1[m]=(f32x4){0,0,0,0};
    aB0[m]=(f32x4){0,0,0,0}; aB1[m]=(f32x4){0,0,0,0};
  }

  #pragma unroll
  for (int ph=0; ph<6; ++ph){
    // ---- 4 score tiles (64 keys) -> unnormalized exp(s-8) -> P chunks
    #pragma unroll
    for (int i=0;i<4;i++){
      const int t = ph*4 + i;
      short8 kf0 = *(const short8*)(kfb + t*2048);
      short8 kf1 = *(const short8*)(kfb + t*2048 + 1024);
      f32x4 s4A = {0,0,0,0}; s4A = MFMA_BF16(kf0,fA0,s4A); s4A = MFMA_BF16(kf1,fA1,s4A);
      f32x4 s4B = {0,0,0,0}; s4B = MFMA_BF16(kf0,fB0,s4B); s4B = MFMA_BF16(kf1,fB1,s4B);
      short4v pA, pB;
      if (ph < 2){
        #pragma unroll
        for (int r=0;r<4;r++){
          float eA = __expf(s4A[r]*0.125f - 8.f); lbA += eA; pA[r] = bf16bits(eA);
          float eB = __expf(s4B[r]*0.125f - 8.f); lbB += eB; pB[r] = bf16bits(eB);
        }
      } else {
        const float aAm = (ph<4)? amA1 : amA2;
        const float aBm = (ph<4)? amB1 : amB2;
        #pragma unroll
        for (int r=0;r<4;r++){
          float eA = aAm*__expf(s4A[r]*0.125f - 8.f); lrA += eA; pA[r] = bf16bits(eA);
          float eB = aBm*__expf(s4B[r]*0.125f - 8.f); lrB += eB; pB[r] = bf16bits(eB);
        }
      }
      *(short4v*)(pwA + i*512)        = pA;  // set A (queries 0-15)
      *(short4v*)(pwA + i*512 + 2048) = pB;  // set B (queries 16-31)
    }
    // ---- 2 PV chunks (32 keys each); V frag shared by both query sets
    #pragma unroll
    for (int klp=0; klp<2; ++klp){
      const int kc = ph*2 + klp;
      short8 pfA = *(const short8*)(prA + klp*1024);
      short8 pfB = *(const short8*)(prA + klp*1024 + 2048);
      #pragma unroll
      for (int m=0;m<4;m++){
        short8 vf = *(const short8*)(vfb + (kc*4 + m)*1024);
        if (ph<2){ aA0[m] = MFMA_BF16(vf,pfA,aA0[m]); aB0[m] = MFMA_BF16(vf,pfB,aB0[m]); }
        else     { aA1[m] = MFMA_BF16(vf,pfA,aA1[m]); aB1[m] = MFMA_BF16(vf,pfB,aB1[m]); }
      }
    }
  }

  // ---- row-sum reductions (query lives in lane&15; reduce across quads)
  lbA += __shfl_xor(lbA,16); lbA += __shfl_xor(lbA,32);
  lrA += __shfl_xor(lrA,16); lrA += __shfl_xor(lrA,32);
  lbB += __shfl_xor(lbB,16); lbB += __shfl_xor(lbB,32);
  lrB += __shfl_xor(lrB,16); lrB += __shfl_xor(lrB,32);

  const float invbA = 0.5f/lbA;
  const float lregA = ((abA&1u)? lbA : 0.f) + lrA;
  const float invrA = 0.5f/lregA;
  const float cA_A  = invbA + ((abA&1u)? invrA : 0.f);

  const float invbB = 0.5f/lbB;
  const float lregB = ((abB&1u)? lbB : 0.f) + lrB;
  const float invrB = 0.5f/lregB;
  const float cA_B  = invbB + ((abB&1u)? invrB : 0.f);

  // ---- store: lane holds d = m*16 + Q*4 + r for its query (fp32, 16B)
  float* obA = out + (size_t)sA*512 + h*64 + Q*4;
  float* obB = out + (size_t)sB*512 + h*64 + Q*4;
  #pragma unroll
  for (int m=0;m<4;m++){
    f32x4 oA, oB;
    #pragma unroll
    for (int r=0;r<4;r++){
      oA[r] = aA0[m][r]*cA_A + aA1[m][r]*invrA;
      oB[r] = aB0[m][r]*cA_B + aB1[m][r]*invrB;
    }
    *(f32x4*)(obA + m*16) = oA;
    *(f32x4*)(obB + m*16) = oB;
  }
}

extern "C" void kernel_launch(void* const* d_in, const int* in_sizes, int n_in,
                              void* d_out, int out_size, void* d_ws, size_t ws_size,
                              hipStream_t stream) {
  const float* q  = (const float*)d_in[0];
  const float* k  = (const float*)d_in[1];
  const float* v  = (const float*)d_in[2];
  const float* rk = (const float*)d_in[3];
  const float* rv = (const float*)d_in[4];
  const float* rm = (const float*)d_in[5];
  float* out = (float*)d_out;

  char* ws = (char*)d_ws;
  unsigned*       allowed = (unsigned*)ws;                           // 56320*4   = 225280 B
  unsigned short* Kb      = (unsigned short*)(ws + 225280);          // 8*3*128*64*2 = 393216 B
  unsigned short* VT      = (unsigned short*)(ws + 225280 + 393216); // 393216 B

  prep_kernel<<<988, 256, 0, stream>>>(rm, k, v, rk, rv, allowed, Kb, VT);
  dim3 grid(220, 8);
  attn_kernel<<<grid, 512, 0, stream>>>(q, allowed, Kb, VT, out);
}

// Round 5
// 347.837 us; speedup vs baseline: 1.0168x; 1.0168x over previous
//
#include <hip/hip_runtime.h>

typedef short short8  __attribute__((ext_vector_type(8)));
typedef short short4v __attribute__((ext_vector_type(4)));
typedef float f32x4   __attribute__((ext_vector_type(4)));

#define MFMA_BF16(A,B,C) __builtin_amdgcn_mfma_f32_16x16x32_bf16((A),(B),(C),0,0,0)

__device__ __forceinline__ short bf16bits(float f){
  return (short)__builtin_bit_cast(unsigned short, static_cast<__bf16>(f));
}

// ---------------- fused preprocessing ----------------
// blocks [0,220): mask preprocessing  (region_masks -> allowed bits)
// blocks [220,988): K/V repack to bf16 in IDENTITY-LANE fragment order:
// each MFMA fragment chunk is 1KB = 64 lanes x 16B with lane l's 16B at
// offset l*16 (lanes 0-7 cover all 32 banks once -> conflict-free linear
// ds_read_b128 by construction; round 4's (c*4+Q) chunk order put 16-lane
// phase groups at 64B stride = bank stride 16 = 8-way conflict).
//   K  chunk (t,f):  lane = Qd*16 + ck   holds K[key=t*16+ck][d=f*32+Qd*8+j]
//   V^T chunk (kc,m): lane = Qv*16 + cv  holds V[key=kc*32+Qv*8+jv][d=m*16+cv]
__global__ __launch_bounds__(256) void prep_kernel(const float* __restrict__ rm,
                                                   const float* __restrict__ k,
                                                   const float* __restrict__ v,
                                                   const float* __restrict__ rk,
                                                   const float* __restrict__ rv,
                                                   unsigned* __restrict__ allowed,
                                                   unsigned short* __restrict__ Kb,
                                                   unsigned short* __restrict__ VT){
  const int bid = blockIdx.x;
  if (bid < 220){
    int s = bid*256 + threadIdx.x;
    if (s >= 56320) return;
    int t = s / 3520;
    int rem = s - t*3520;
    int i = rem / 80;
    int j = rem - i*80;
    int y = 2*i, x = 2*j;
    bool bin[2];
    #pragma unroll
    for (int r=0;r<2;r++){
      const float* base = rm + (size_t)r*121*88*160;
      float acc;
      if (t == 0){
        const float* p0 = base + (size_t)(0*88 + y)*160 + x;
        acc = 0.25f*(p0[0]+p0[1]+p0[160]+p0[161]);
      } else {
        const float* pa = base + (size_t)((8*t-4)*88 + y)*160 + x;
        const float* pb = base + (size_t)((8*t-3)*88 + y)*160 + x;
        acc = 0.125f*(pa[0]+pa[1]+pa[160]+pa[161] + pb[0]+pb[1]+pb[160]+pb[161]);
      }
      bin[r] = acc > 0.5f;
    }
    unsigned bits = (bin[0]||bin[1]) ? 0u : 1u;
    if (bin[0]) bits |= 2u;
    if (bin[1]) bits |= 4u;
    allowed[s] = bits;
  } else {
    int idx = (bid-220)*256 + threadIdx.x;   // over 3*128*8*64 = 196608
    if (idx >= 3*128*8*64) return;
    int d   = idx & 63;
    int h   = (idx >> 6) & 7;
    int p   = (idx >> 9) & 127;
    int seg = idx >> 16;
    int low = idx & 65535;                   // (p*8+h)*64+d
    float kv_, vv_;
    if (seg == 0){ kv_ = k[low];                          vv_ = v[low]; }
    else         { kv_ = rk[(size_t)(seg-1)*65536 + low]; vv_ = rv[(size_t)(seg-1)*65536 + low]; }
    const int kk = seg*128 + p;              // key index within head, 0..383
    // K: chunk (t=kk>>4, f=d>>5), lane = ((d>>3)&3)*16 + (kk&15), elem j=d&7
    Kb[(size_t)h*24576 + ((kk>>4)*2 + (d>>5))*512
       + ((((d>>3)&3)*16) + (kk&15))*8 + (d&7)] = (unsigned short)bf16bits(kv_);
    // V^T: chunk (kc=kk>>5, m=d>>4), lane = ((kk>>3)&3)*16 + (d&15), elem jv=kk&7
    VT[(size_t)h*24576 + ((kk>>5)*4 + (d>>4))*512
       + ((((kk>>3)&3)*16) + (d&15))*8 + (kk&7)] = (unsigned short)bf16bits(vv_);
  }
}

// ---------------- fused regional+base attention, LDS-staged ----------------
// 512 threads (8 waves) per (head, 256-query chunk). K (48KB) + V^T (48KB)
// staged once per block as a pure linear memcpy (fragment permutation done in
// prep). Every hot-loop ds_read_b128 is lane*16 linear -> conflict-free.
// Each wave owns 32 queries (sets A/B sharing every K/V fragment read).
// 6 phases of {4 score tiles -> unnormalized exp(s-8) -> P chunks; 2 PV}.
// P storage (per wave, per set, per phase-local kc chunk): byte addr of
// (key-local kl, query qy) = ((kl>>3)*16 + qy)*16 + (kl&7)*2 -> read is
// lane*16 linear; write is short4v at 2-way-aliased banks (free).
// LDS = 48+48+32 = 128KB -> 1 block/CU, 2 waves/SIMD.
// amdgpu_waves_per_eu(2,2): pins min AND max occupancy so the allocator has
// no incentive to shrink below the 256-VGPR budget (rounds 1/3/4: scheduler
// chased occupancy past the declared minimum and spilled ~40 f32/thread,
// +140MB scratch WRITE_SIZE).
__global__ __launch_bounds__(512)
__attribute__((amdgpu_waves_per_eu(2, 2)))
void attn_kernel(const float* __restrict__ q,
                 const unsigned* __restrict__ allowed,
                 const unsigned short* __restrict__ Kb,
                 const unsigned short* __restrict__ VT,
                 float* __restrict__ out){
  const int h    = blockIdx.y;
  const int wave = threadIdx.x >> 6;
  const int lane = threadIdx.x & 63;
  const int c    = lane & 15;        // query col within set / fragment row
  const int Q    = lane >> 4;        // quad

  __shared__ __align__(16) char Ks[49152];   // 24 tiles x 2 frags x 1KB
  __shared__ __align__(16) char Vs[49152];   // 12 kc x 4 m chunks x 1KB
  __shared__ __align__(16) char Ps[32768];   // 8 waves x 2 sets x 2KB (phase-local)

  const int sA = blockIdx.x*256 + wave*32 + c;
  const int sB = sA + 16;

  // ---- early global loads (overlap with staging)
  const unsigned abA = allowed[sA], abB = allowed[sB];
  const float* qpA = q + ((size_t)sA*8 + h)*64 + Q*8;
  const float* qpB = q + ((size_t)sB*8 + h)*64 + Q*8;
  f32x4 qA0 = *(const f32x4*)(qpA);
  f32x4 qA1 = *(const f32x4*)(qpA+4);
  f32x4 qA2 = *(const f32x4*)(qpA+32);
  f32x4 qA3 = *(const f32x4*)(qpA+36);
  f32x4 qB0 = *(const f32x4*)(qpB);
  f32x4 qB1 = *(const f32x4*)(qpB+4);
  f32x4 qB2 = *(const f32x4*)(qpB+32);
  f32x4 qB3 = *(const f32x4*)(qpB+36);

  // ---- stage K and V^T: pure linear copy, 6KB of each per wave
  {
    const char* kg = (const char*)Kb + (size_t)h*49152;
    const char* vg = (const char*)VT + (size_t)h*49152;
    #pragma unroll
    for (int i=0;i<6;i++){
      const int off = wave*6144 + i*1024 + lane*16;
      short8 kval = *(const short8*)(kg + off);
      short8 vval = *(const short8*)(vg + off);
      *(short8*)(Ks + off) = kval;
      *(short8*)(Vs + off) = vval;
    }
  }

  // ---- bf16 Q fragments (B-operand): lane holds q[s(c)][d=Q*8+j (+32)]
  short8 fA0, fA1, fB0, fB1;
  #pragma unroll
  for (int j=0;j<4;j++){
    fA0[j] = bf16bits(qA0[j]); fA0[4+j] = bf16bits(qA1[j]);
    fA1[j] = bf16bits(qA2[j]); fA1[4+j] = bf16bits(qA3[j]);
    fB0[j] = bf16bits(qB0[j]); fB0[4+j] = bf16bits(qB1[j]);
    fB1[j] = bf16bits(qB2[j]); fB1[4+j] = bf16bits(qB3[j]);
  }

  __syncthreads();   // staged K/V visible to all waves

  // ---- identity-lane fragment bases (linear, conflict-free)
  const char* kfb = Ks + lane*16;            // + (t*2+f)*1024
  const char* vfb = Vs + lane*16;            // + (kc*4+m)*1024
  char*       pwb = Ps + wave*4096 + (Q>>1)*256 + c*16 + (Q&1)*8; // + (i>>1)*1024 + (i&1)*512 (+2048 set B)
  const char* prb = Ps + wave*4096 + lane*16;                     // + klp*1024 (+2048 set B)

  const float amA1 = (abA>>1)&1u ? 1.f : 0.f;
  const float amA2 = (abA>>2)&1u ? 1.f : 0.f;
  const float amB1 = (abB>>1)&1u ? 1.f : 0.f;
  const float amB2 = (abB>>2)&1u ? 1.f : 0.f;

  float lbA=0.f, lrA=0.f, lbB=0.f, lrB=0.f;
  f32x4 aA0[4], aA1[4], aB0[4], aB1[4];
  #pragma unroll
  for (int m=0;m<4;m++){
    aA0[m]=(f32x4){0,0,0,0}; aA1[m]=(f32x4){0,0,0,0};
    aB0[m]=(f32x4){0,0,0,0}; aB1[m]=(f32x4){0,0,0,0};
  }

  #pragma unroll
  for (int ph=0; ph<6; ++ph){
    // ---- 4 score tiles (64 keys) -> unnormalized exp(s-8) -> P chunks
    #pragma unroll
    for (int i=0;i<4;i++){
      const int t = ph*4 + i;
      short8 kf0 = *(const short8*)(kfb + (t*2  )*1024);
      short8 kf1 = *(const short8*)(kfb + (t*2+1)*1024);
      f32x4 s4A = {0,0,0,0}; s4A = MFMA_BF16(kf0,fA0,s4A); s4A = MFMA_BF16(kf1,fA1,s4A);
      f32x4 s4B = {0,0,0,0}; s4B = MFMA_BF16(kf0,fB0,s4B); s4B = MFMA_BF16(kf1,fB1,s4B);
      short4v pA, pB;
      if (ph < 2){
        #pragma unroll
        for (int r=0;r<4;r++){
          float eA = __expf(s4A[r]*0.125f - 8.f); lbA += eA; pA[r] = bf16bits(eA);
          float eB = __expf(s4B[r]*0.125f - 8.f); lbB += eB; pB[r] = bf16bits(eB);
        }
      } else {
        const float aAm = (ph<4)? amA1 : amA2;
        const float aBm = (ph<4)? amB1 : amB2;
        #pragma unroll
        for (int r=0;r<4;r++){
          float eA = aAm*__expf(s4A[r]*0.125f - 8.f); lrA += eA; pA[r] = bf16bits(eA);
          float eB = aBm*__expf(s4B[r]*0.125f - 8.f); lrB += eB; pB[r] = bf16bits(eB);
        }
      }
      const int po = (i>>1)*1024 + (i&1)*512;
      *(short4v*)(pwb + po)        = pA;  // set A (queries 0-15)
      *(short4v*)(pwb + po + 2048) = pB;  // set B (queries 16-31)
    }
    // ---- 2 PV chunks (32 keys each); V frag shared by both query sets
    #pragma unroll
    for (int klp=0; klp<2; ++klp){
      const int kc = ph*2 + klp;
      short8 pfA = *(const short8*)(prb + klp*1024);
      short8 pfB = *(const short8*)(prb + klp*1024 + 2048);
      #pragma unroll
      for (int m=0;m<4;m++){
        short8 vf = *(const short8*)(vfb + (kc*4 + m)*1024);
        if (ph<2){ aA0[m] = MFMA_BF16(vf,pfA,aA0[m]); aB0[m] = MFMA_BF16(vf,pfB,aB0[m]); }
        else     { aA1[m] = MFMA_BF16(vf,pfA,aA1[m]); aB1[m] = MFMA_BF16(vf,pfB,aB1[m]); }
      }
    }
  }

  // ---- row-sum reductions (query lives in lane&15; reduce across quads)
  lbA += __shfl_xor(lbA,16); lbA += __shfl_xor(lbA,32);
  lrA += __shfl_xor(lrA,16); lrA += __shfl_xor(lrA,32);
  lbB += __shfl_xor(lbB,16); lbB += __shfl_xor(lbB,32);
  lrB += __shfl_xor(lrB,16); lrB += __shfl_xor(lrB,32);

  const float invbA = 0.5f/lbA;
  const float lregA = ((abA&1u)? lbA : 0.f) + lrA;
  const float invrA = 0.5f/lregA;
  const float cA_A  = invbA + ((abA&1u)? invrA : 0.f);

  const float invbB = 0.5f/lbB;
  const float lregB = ((abB&1u)? lbB : 0.f) + lrB;
  const float invrB = 0.5f/lregB;
  const float cA_B  = invbB + ((abB&1u)? invrB : 0.f);

  // ---- store: lane holds d = m*16 + Q*4 + r for its query (fp32, 16B)
  float* obA = out + (size_t)sA*512 + h*64 + Q*4;
  float* obB = out + (size_t)sB*512 + h*64 + Q*4;
  #pragma unroll
  for (int m=0;m<4;m++){
    f32x4 oA, oB;
    #pragma unroll
    for (int r=0;r<4;r++){
      oA[r] = aA0[m][r]*cA_A + aA1[m][r]*invrA;
      oB[r] = aB0[m][r]*cA_B + aB1[m][r]*invrB;
    }
    *(f32x4*)(obA + m*16) = oA;
    *(f32x4*)(obB + m*16) = oB;
  }
}

extern "C" void kernel_launch(void* const* d_in, const int* in_sizes, int n_in,
                              void* d_out, int out_size, void* d_ws, size_t ws_size,
                              hipStream_t stream) {
  const float* q  = (const float*)d_in[0];
  const float* k  = (const float*)d_in[1];
  const float* v  = (const float*)d_in[2];
  const float* rk = (const float*)d_in[3];
  const float* rv = (const float*)d_in[4];
  const float* rm = (const float*)d_in[5];
  float* out = (float*)d_out;

  char* ws = (char*)d_ws;
  unsigned*       allowed = (unsigned*)ws;                           // 56320*4   = 225280 B
  unsigned short* Kb      = (unsigned short*)(ws + 225280);          // 8*3*128*64*2 = 393216 B
  unsigned short* VT      = (unsigned short*)(ws + 225280 + 393216); // 393216 B

  prep_kernel<<<988, 256, 0, stream>>>(rm, k, v, rk, rv, allowed, Kb, VT);
  dim3 grid(220, 8);
  attn_kernel<<<grid, 512, 0, stream>>>(q, allowed, Kb, VT, out);
}